// Round 1
// baseline (363.097 us; speedup 1.0000x reference)
//
#include <hip/hip_runtime.h>

typedef __attribute__((ext_vector_type(8))) short bf16x8;
typedef __attribute__((ext_vector_type(4))) float f32x4;

#define NCOL 352
#define KSLICE (NCOL * 32) /* shorts per 32-k slice */
#define BROWS 65536

static __device__ __forceinline__ unsigned int bf16rne(float f) {
  unsigned int u = __float_as_uint(f);
  return (u + 0x7FFFu + ((u >> 16) & 1u)) >> 16;
}

static __device__ __forceinline__ unsigned int pack2(float a, float b) {
  return bf16rne(a) | (bf16rne(b) << 16);
}

// Pack weights -> bf16 Wpack[(k/32)][col][k%32], and bias[352].
// Column map: [0,100) task0 (e*10+h), [100,200) task1, [200,300) shared,
// [300,340) gates (t*20+g), [340,352) zero pad.
__global__ void ple_prep(const float* __restrict__ Ws, const float* __restrict__ bs,
                         const float* __restrict__ Wt, const float* __restrict__ bt,
                         const float* __restrict__ Wg, const float* __restrict__ bg,
                         unsigned short* __restrict__ Wpack, float* __restrict__ bias) {
  const int n = blockIdx.x;   // 0..351
  const int tid = threadIdx.x;
  const float* src = nullptr;
  int stride = 0;
  float bval = 0.f;
  if (n < 200) {
    int t = n / 100, m = n % 100, e = m / 10, h = m % 10;
    src = Wt + (size_t)(t * 10 + e) * 10240 + h;
    stride = 10;
    bval = bt[(t * 10 + e) * 10 + h];
  } else if (n < 300) {
    int m = n - 200, e = m / 10, h = m % 10;
    src = Ws + (size_t)e * 10240 + h;
    stride = 10;
    bval = bs[e * 10 + h];
  } else if (n < 340) {
    int m = n - 300, t = m / 20, g = m % 20;
    src = Wg + (size_t)t * 20480 + g;
    stride = 20;
    bval = bg[t * 20 + g];
  }
  for (int j = 0; j < 4; j++) {
    int k = tid + j * 256;
    float v = src ? src[(size_t)k * stride] : 0.f;
    Wpack[(size_t)(k >> 5) * KSLICE + n * 32 + (k & 31)] = (unsigned short)bf16rne(v);
  }
  if (tid == 0) bias[n] = bval;
}

// Main fused kernel: 64 rows/block, 4 waves as 2(M)x2(N).
__global__ __launch_bounds__(256, 3) void ple_main(
    const float* __restrict__ x, const unsigned short* __restrict__ Wpack,
    const float* __restrict__ bias, const float* __restrict__ Wc,
    const float* __restrict__ bc, const float* __restrict__ Wv,
    const float* __restrict__ bv, float* __restrict__ out) {
  __shared__ unsigned short xs[64 * 40];  // x tile bf16, k-stride padded 32->40
  __shared__ float z[32 * 357];           // epilogue dump, odd stride

  const int tid = threadIdx.x;
  const int l = tid & 63;
  const int w = tid >> 6;
  const int wm = w >> 1, wn = w & 1;
  const int rowbase = blockIdx.x * 64;

  const f32x4 fzero = {0.f, 0.f, 0.f, 0.f};
  f32x4 acc[2][11];
#pragma unroll
  for (int i = 0; i < 2; ++i)
#pragma unroll
    for (int j = 0; j < 11; ++j) acc[i][j] = fzero;

  // staging: thread -> (row, k-subsegment of 8)
  const int srow = tid >> 2, ksub = tid & 3;
  const float* xg = x + (size_t)(rowbase + srow) * 1024 + ksub * 8;
  unsigned short* xsw = &xs[srow * 40 + ksub * 8];

  // mfma fragment addressing
  const int arow = l & 15, ablk = l >> 4;
  const unsigned short* xa0 = &xs[(wm * 32 + arow) * 40 + ablk * 8];
  const unsigned short* xa1 = xa0 + 16 * 40;
  const unsigned short* wb = Wpack + (wn * 176 + arow) * 32 + ablk * 8;

  for (int ks = 0; ks < 32; ks++) {
    float4 v0 = *(const float4*)(xg + ks * 32);
    float4 v1 = *(const float4*)(xg + ks * 32 + 4);
    unsigned int p0 = pack2(v0.x, v0.y), p1 = pack2(v0.z, v0.w);
    unsigned int p2 = pack2(v1.x, v1.y), p3 = pack2(v1.z, v1.w);
    __syncthreads();  // previous iter's frag reads done before overwrite
    *(uint4*)xsw = make_uint4(p0, p1, p2, p3);
    __syncthreads();
    bf16x8 a0 = *(const bf16x8*)xa0;
    bf16x8 a1 = *(const bf16x8*)xa1;
    const unsigned short* wk = wb + (size_t)ks * KSLICE;
#pragma unroll
    for (int nt = 0; nt < 11; nt++) {
      bf16x8 bf = *(const bf16x8*)(wk + nt * 512);
      acc[0][nt] = __builtin_amdgcn_mfma_f32_16x16x32_bf16(a0, bf, acc[0][nt], 0, 0, 0);
      acc[1][nt] = __builtin_amdgcn_mfma_f32_16x16x32_bf16(a1, bf, acc[1][nt], 0, 0, 0);
    }
  }

  // Epilogue: two 32-row phases. D layout: row=(l>>4)*4+reg, col=l&15.
  for (int half = 0; half < 2; half++) {
    __syncthreads();
    if (wm == half) {
#pragma unroll
      for (int mf = 0; mf < 2; mf++)
#pragma unroll
        for (int nt = 0; nt < 11; nt++)
#pragma unroll
          for (int r = 0; r < 4; r++)
            z[(mf * 16 + ablk * 4 + r) * 357 + wn * 176 + nt * 16 + arow] =
                acc[mf][nt][r];
    }
    __syncthreads();
    if (tid < 64) {
      const int t = tid >> 5, r = tid & 31;
      const float* zr = &z[r * 357];
      // gate softmax over 20 logits
      float gl[20], m = -1e30f;
#pragma unroll
      for (int u = 0; u < 20; u++) {
        gl[u] = zr[300 + t * 20 + u] + bias[300 + t * 20 + u];
        m = fmaxf(m, gl[u]);
      }
      float p[20], s = 0.f;
#pragma unroll
      for (int u = 0; u < 20; u++) {
        p[u] = __expf(gl[u] - m);
        s += p[u];
      }
      const float inv = 1.f / s;
      const float* Wl = t ? Wv : Wc;
      float wl[10];
#pragma unroll
      for (int h = 0; h < 10; h++) wl[h] = Wl[h];
      float accum = 0.f;
#pragma unroll
      for (int u = 0; u < 10; u++) {  // task experts
        float d = 0.f;
#pragma unroll
        for (int h = 0; h < 10; h++) {
          int c = t * 100 + u * 10 + h;
          d += fmaxf(zr[c] + bias[c], 0.f) * wl[h];
        }
        accum += p[u] * d;
      }
#pragma unroll
      for (int u = 0; u < 10; u++) {  // shared experts
        float d = 0.f;
#pragma unroll
        for (int h = 0; h < 10; h++) {
          int c = 200 + u * 10 + h;
          d += fmaxf(zr[c] + bias[c], 0.f) * wl[h];
        }
        accum += p[10 + u] * d;
      }
      float logit = (t ? bv[0] : bc[0]) + accum * inv;
      out[(size_t)t * BROWS + rowbase + half * 32 + r] =
          1.f / (1.f + __expf(-logit));
    }
  }
}

extern "C" void kernel_launch(void* const* d_in, const int* in_sizes, int n_in,
                              void* d_out, int out_size, void* d_ws, size_t ws_size,
                              hipStream_t stream) {
  const float* x = (const float*)d_in[0];
  const float* Ws = (const float*)d_in[3];
  const float* bs = (const float*)d_in[4];
  const float* Wt = (const float*)d_in[5];
  const float* bt = (const float*)d_in[6];
  const float* Wg = (const float*)d_in[7];
  const float* bg = (const float*)d_in[8];
  const float* Wc = (const float*)d_in[9];
  const float* bc = (const float*)d_in[10];
  const float* Wv = (const float*)d_in[11];
  const float* bv = (const float*)d_in[12];
  unsigned short* Wpack = (unsigned short*)d_ws;
  float* bias = (float*)((char*)d_ws + (size_t)NCOL * 1024 * 2);
  float* out = (float*)d_out;

  hipLaunchKernelGGL(ple_prep, dim3(352), dim3(256), 0, stream, Ws, bs, Wt, bt,
                     Wg, bg, Wpack, bias);
  hipLaunchKernelGGL(ple_main, dim3(1024), dim3(256), 0, stream, x, Wpack, bias,
                     Wc, bc, Wv, bv, out);
}

// Round 2
// 264.222 us; speedup vs baseline: 1.3742x; 1.3742x over previous
//
#include <hip/hip_runtime.h>
#include <hip/hip_bf16.h>

typedef __attribute__((ext_vector_type(8))) short bf16x8;
typedef __attribute__((ext_vector_type(4))) float f32x4;

#define NCOL 352
#define KSLICE (NCOL * 32) /* shorts per 32-k slice */
#define BROWS 65536

static __device__ __forceinline__ unsigned int bf16rne(float f) {
  unsigned int u = __float_as_uint(f);
  return (u + 0x7FFFu + ((u >> 16) & 1u)) >> 16;
}

static __device__ __forceinline__ unsigned int pack2(float a, float b) {
  __hip_bfloat162 h = __float22bfloat162_rn(make_float2(a, b));
  return *reinterpret_cast<unsigned int*>(&h);
}

// Pack weights -> bf16 Wpack[(k/32)][col][k%32], and bias[352].
// Column map: [0,100) task0 (e*10+h), [100,200) task1, [200,300) shared,
// [300,340) gates (t*20+g), [340,352) zero pad.
__global__ void ple_prep(const float* __restrict__ Ws, const float* __restrict__ bs,
                         const float* __restrict__ Wt, const float* __restrict__ bt,
                         const float* __restrict__ Wg, const float* __restrict__ bg,
                         unsigned short* __restrict__ Wpack, float* __restrict__ bias) {
  const int n = blockIdx.x;   // 0..351
  const int tid = threadIdx.x;
  const float* src = nullptr;
  int stride = 0;
  float bval = 0.f;
  if (n < 200) {
    int t = n / 100, m = n % 100, e = m / 10, h = m % 10;
    src = Wt + (size_t)(t * 10 + e) * 10240 + h;
    stride = 10;
    bval = bt[(t * 10 + e) * 10 + h];
  } else if (n < 300) {
    int m = n - 200, e = m / 10, h = m % 10;
    src = Ws + (size_t)e * 10240 + h;
    stride = 10;
    bval = bs[e * 10 + h];
  } else if (n < 340) {
    int m = n - 300, t = m / 20, g = m % 20;
    src = Wg + (size_t)t * 20480 + g;
    stride = 20;
    bval = bg[t * 20 + g];
  }
  for (int j = 0; j < 4; j++) {
    int k = tid + j * 256;
    float v = src ? src[(size_t)k * stride] : 0.f;
    Wpack[(size_t)(k >> 5) * KSLICE + n * 32 + (k & 31)] = (unsigned short)bf16rne(v);
  }
  if (tid == 0) bias[n] = bval;
}

// Main fused kernel: 64 rows/block, 4 waves as 2(M)x2(N).
// No LDS / no barriers in the K-loop: A-fragments loaded per-lane from
// global (fp32 -> bf16 cvt in-register), B-fragments from L2-resident Wpack.
__global__ __launch_bounds__(256, 3) void ple_main(
    const float* __restrict__ x, const unsigned short* __restrict__ Wpack,
    const float* __restrict__ bias, const float* __restrict__ Wc,
    const float* __restrict__ bc, const float* __restrict__ Wv,
    const float* __restrict__ bv, float* __restrict__ out) {
  __shared__ float z[32 * 357];  // epilogue dump, odd stride -> conflict-free

  const int tid = threadIdx.x;
  const int l = tid & 63;
  const int w = tid >> 6;
  const int wm = w >> 1, wn = w & 1;
  const int rowbase = blockIdx.x * 64;
  const int arow = l & 15, ablk = l >> 4;

  const f32x4 fzero = {0.f, 0.f, 0.f, 0.f};
  f32x4 acc[2][11];
#pragma unroll
  for (int i = 0; i < 2; ++i)
#pragma unroll
    for (int j = 0; j < 11; ++j) acc[i][j] = fzero;

  // A-fragment global addresses: row = rowbase + wm*32 + mf*16 + (l&15),
  // k = ks*32 + (l>>4)*8 + i  (A and B share this k-order per lane -> valid)
  const float* xg0 = x + (size_t)(rowbase + wm * 32 + arow) * 1024 + ablk * 8;
  const float* xg1 = xg0 + 16 * 1024;
  const unsigned short* wb = Wpack + (wn * 176 + arow) * 32 + ablk * 8;

  float4 ra00 = *(const float4*)(xg0);
  float4 ra01 = *(const float4*)(xg0 + 4);
  float4 ra10 = *(const float4*)(xg1);
  float4 ra11 = *(const float4*)(xg1 + 4);

#pragma unroll 2
  for (int ks = 0; ks < 32; ks++) {
    union { bf16x8 v; uint4 u; } A0, A1;
    A0.u = make_uint4(pack2(ra00.x, ra00.y), pack2(ra00.z, ra00.w),
                      pack2(ra01.x, ra01.y), pack2(ra01.z, ra01.w));
    A1.u = make_uint4(pack2(ra10.x, ra10.y), pack2(ra10.z, ra10.w),
                      pack2(ra11.x, ra11.y), pack2(ra11.z, ra11.w));
    if (ks < 31) {  // prefetch next K-step's A raw data
      const float* n0 = xg0 + (ks + 1) * 32;
      const float* n1 = xg1 + (ks + 1) * 32;
      ra00 = *(const float4*)(n0);
      ra01 = *(const float4*)(n0 + 4);
      ra10 = *(const float4*)(n1);
      ra11 = *(const float4*)(n1 + 4);
    }
    const unsigned short* wk = wb + (size_t)ks * KSLICE;
#pragma unroll
    for (int nt = 0; nt < 11; nt++) {
      bf16x8 bf = *(const bf16x8*)(wk + nt * 512);
      acc[0][nt] = __builtin_amdgcn_mfma_f32_16x16x32_bf16(A0.v, bf, acc[0][nt], 0, 0, 0);
      acc[1][nt] = __builtin_amdgcn_mfma_f32_16x16x32_bf16(A1.v, bf, acc[1][nt], 0, 0, 0);
    }
  }

  // Epilogue: two 32-row phases. D layout: row=(l>>4)*4+reg, col=l&15.
  for (int half = 0; half < 2; half++) {
    __syncthreads();
    if (wm == half) {
#pragma unroll
      for (int mf = 0; mf < 2; mf++)
#pragma unroll
        for (int nt = 0; nt < 11; nt++)
#pragma unroll
          for (int r = 0; r < 4; r++)
            z[(mf * 16 + ablk * 4 + r) * 357 + wn * 176 + nt * 16 + arow] =
                acc[mf][nt][r];
    }
    __syncthreads();
    if (tid < 64) {
      const int t = tid >> 5, r = tid & 31;
      const float* zr = &z[r * 357];
      // gate softmax over 20 logits
      float gl[20], m = -1e30f;
#pragma unroll
      for (int u = 0; u < 20; u++) {
        gl[u] = zr[300 + t * 20 + u] + bias[300 + t * 20 + u];
        m = fmaxf(m, gl[u]);
      }
      float p[20], s = 0.f;
#pragma unroll
      for (int u = 0; u < 20; u++) {
        p[u] = __expf(gl[u] - m);
        s += p[u];
      }
      const float inv = 1.f / s;
      const float* Wl = t ? Wv : Wc;
      float wl[10];
#pragma unroll
      for (int h = 0; h < 10; h++) wl[h] = Wl[h];
      float accum = 0.f;
#pragma unroll
      for (int u = 0; u < 10; u++) {  // task experts
        float d = 0.f;
#pragma unroll
        for (int h = 0; h < 10; h++) {
          int c = t * 100 + u * 10 + h;
          d += fmaxf(zr[c] + bias[c], 0.f) * wl[h];
        }
        accum += p[u] * d;
      }
#pragma unroll
      for (int u = 0; u < 10; u++) {  // shared experts
        float d = 0.f;
#pragma unroll
        for (int h = 0; h < 10; h++) {
          int c = 200 + u * 10 + h;
          d += fmaxf(zr[c] + bias[c], 0.f) * wl[h];
        }
        accum += p[10 + u] * d;
      }
      float logit = (t ? bv[0] : bc[0]) + accum * inv;
      out[(size_t)t * BROWS + rowbase + half * 32 + r] =
          1.f / (1.f + __expf(-logit));
    }
  }
}

extern "C" void kernel_launch(void* const* d_in, const int* in_sizes, int n_in,
                              void* d_out, int out_size, void* d_ws, size_t ws_size,
                              hipStream_t stream) {
  const float* x = (const float*)d_in[0];
  const float* Ws = (const float*)d_in[3];
  const float* bs = (const float*)d_in[4];
  const float* Wt = (const float*)d_in[5];
  const float* bt = (const float*)d_in[6];
  const float* Wg = (const float*)d_in[7];
  const float* bg = (const float*)d_in[8];
  const float* Wc = (const float*)d_in[9];
  const float* bc = (const float*)d_in[10];
  const float* Wv = (const float*)d_in[11];
  const float* bv = (const float*)d_in[12];
  unsigned short* Wpack = (unsigned short*)d_ws;
  float* bias = (float*)((char*)d_ws + (size_t)NCOL * 1024 * 2);
  float* out = (float*)d_out;

  hipLaunchKernelGGL(ple_prep, dim3(352), dim3(256), 0, stream, Ws, bs, Wt, bt,
                     Wg, bg, Wpack, bias);
  hipLaunchKernelGGL(ple_main, dim3(1024), dim3(256), 0, stream, x, Wpack, bias,
                     Wc, bc, Wv, bv, out);
}

// Round 3
// 111.329 us; speedup vs baseline: 3.2615x; 2.3733x over previous
//
#include <hip/hip_runtime.h>
#include <hip/hip_bf16.h>

typedef __attribute__((ext_vector_type(8))) short bf16x8;
typedef __attribute__((ext_vector_type(4))) float f32x4;

#define NCOLP 384                 // padded columns (352 real + 32 zero)
#define STEP_SHORTS (NCOLP * 32)  // 12288 shorts = 24576 B per 32-k step
#define STEP_BYTES (STEP_SHORTS * 2)
#define NSTEP 32
#define BROWS 65536
#define ABLK_LDS (NCOLP * 16 + 16) /* 6160 B per ablk segment (16B bank pad) */
#define SLOT_LDS (4 * ABLK_LDS)    /* 24640 B per ring slot */

static __device__ __forceinline__ unsigned int bf16rne(float f) {
  unsigned int u = __float_as_uint(f);
  return (u + 0x7FFFu + ((u >> 16) & 1u)) >> 16;
}
static __device__ __forceinline__ unsigned int pack2(float a, float b) {
  return bf16rne(a) | (bf16rne(b) << 16);
}
static __device__ __forceinline__ void gload16(const void* g, void* l) {
  __builtin_amdgcn_global_load_lds(
      (const __attribute__((address_space(1))) unsigned int*)g,
      (__attribute__((address_space(3))) unsigned int*)l, 16, 0, 0);
}

// Wpack layout: [step][ablk(4)][col(384)][k%8]  (bf16), step = 24576 B.
// Column map: [0,100) task0 (e*10+h), [100,200) task1, [200,300) shared,
// [300,340) gates (t*20+g), [340,384) zero pad.
__global__ void ple_prep(const float* __restrict__ Ws, const float* __restrict__ bs,
                         const float* __restrict__ Wt, const float* __restrict__ bt,
                         const float* __restrict__ Wg, const float* __restrict__ bg,
                         unsigned short* __restrict__ Wpack, float* __restrict__ bias) {
  const int n = blockIdx.x;  // 0..383
  const int tid = threadIdx.x;
  const float* src = nullptr;
  int stride = 0;
  float bval = 0.f;
  if (n < 200) {
    int t = n / 100, m = n % 100, e = m / 10, h = m % 10;
    src = Wt + (size_t)(t * 10 + e) * 10240 + h;
    stride = 10;
    bval = bt[(t * 10 + e) * 10 + h];
  } else if (n < 300) {
    int m = n - 200, e = m / 10, h = m % 10;
    src = Ws + (size_t)e * 10240 + h;
    stride = 10;
    bval = bs[e * 10 + h];
  } else if (n < 340) {
    int m = n - 300, t = m / 20, g = m % 20;
    src = Wg + (size_t)t * 20480 + g;
    stride = 20;
    bval = bg[t * 20 + g];
  }
  for (int j = 0; j < 4; j++) {
    int k = tid + j * 256;
    float v = src ? src[(size_t)k * stride] : 0.f;
    Wpack[(size_t)(k >> 5) * STEP_SHORTS + ((k >> 3) & 3) * (NCOLP * 8) + n * 8 +
          (k & 7)] = (unsigned short)bf16rne(v);
  }
  if (tid == 0 && n < 352) bias[n] = bval;
}

// Main: 512 threads = 8 waves (4M x 2N), 128 rows/block, N=352.
// A: global->reg depth-2 ring. B: global->LDS ring (2 slots) via
// global_load_lds with counted vmcnt + raw barriers.
__global__ __launch_bounds__(512, 2) void ple_main(
    const float* __restrict__ x, const unsigned short* __restrict__ Wpack,
    const float* __restrict__ bias, const float* __restrict__ Wc,
    const float* __restrict__ bc, const float* __restrict__ Wv,
    const float* __restrict__ bv, float* __restrict__ out) {
  __shared__ __align__(16) char smem[2 * SLOT_LDS];  // 49280 B; epilogue z aliases
  float* z = (float*)smem;                           // [32][357] = 45696 B

  const int tid = threadIdx.x;
  const int l = tid & 63, w = tid >> 6;
  const int wm = w >> 1, wn = w & 1;  // wm 0..3, wn 0..1
  const int arow = l & 15, ablk = l >> 4;
  const int rowbase = blockIdx.x * 128;

  const f32x4 fzero = {0.f, 0.f, 0.f, 0.f};
  f32x4 acc[2][11];
#pragma unroll
  for (int i = 0; i < 2; ++i)
#pragma unroll
    for (int j = 0; j < 11; ++j) acc[i][j] = fzero;

  // A addressing: frag mf rows = rowbase + wm*32 + mf*16 + arow, k = ks*32+ablk*8+i
  const float* xg0 = x + (size_t)(rowbase + wm * 32 + arow) * 1024 + ablk * 8;
  const float* xg1 = xg0 + 16 * 1024;

  // B staging: chunk c = w*3+j, global byte off = c*1024 + l*16 (within step),
  // LDS byte off = same + (c/6)*16 (per-ablk pad).
  const int c0 = w * 3;
  const char* wsrc = (const char*)Wpack + c0 * 1024 + l * 16;
  char* ldst0 = smem + c0 * 1024 + (c0 / 6) * 16 + l * 16;
  char* ldst1 = smem + (c0 + 1) * 1024 + ((c0 + 1) / 6) * 16 + l * 16;
  char* ldst2 = smem + (c0 + 2) * 1024 + ((c0 + 2) / 6) * 16 + l * 16;

  // B read base: ablk*6160 + (wn*176 + nt*16 + arow)*16
  const char* brd = smem + ablk * ABLK_LDS + (wn * 176 + arow) * 16;

  // ---- prologue: stage B(0) -> slot 0, then A(0), A(1) ----
  gload16(wsrc, ldst0);
  gload16(wsrc + 1024, ldst1);
  gload16(wsrc + 2048, ldst2);
  __builtin_amdgcn_sched_barrier(0);
  float4 ra[2][4];
  ra[0][0] = *(const float4*)(xg0);
  ra[0][1] = *(const float4*)(xg0 + 4);
  ra[0][2] = *(const float4*)(xg1);
  ra[0][3] = *(const float4*)(xg1 + 4);
  __builtin_amdgcn_sched_barrier(0);
  ra[1][0] = *(const float4*)(xg0 + 32);
  ra[1][1] = *(const float4*)(xg0 + 36);
  ra[1][2] = *(const float4*)(xg1 + 32);
  ra[1][3] = *(const float4*)(xg1 + 36);
  __builtin_amdgcn_sched_barrier(0);

#pragma unroll 2
  for (int ks = 0; ks < NSTEP; ks++) {
    const int cur = ks & 1;
    // 1) convert A[cur] -> bf16 frags (compiler waits its own loads precisely)
    union { bf16x8 v; uint4 u; } A0, A1;
    A0.u = make_uint4(pack2(ra[cur][0].x, ra[cur][0].y), pack2(ra[cur][0].z, ra[cur][0].w),
                      pack2(ra[cur][1].x, ra[cur][1].y), pack2(ra[cur][1].z, ra[cur][1].w));
    A1.u = make_uint4(pack2(ra[cur][2].x, ra[cur][2].y), pack2(ra[cur][2].z, ra[cur][2].w),
                      pack2(ra[cur][3].x, ra[cur][3].y), pack2(ra[cur][3].z, ra[cur][3].w));
    __builtin_amdgcn_sched_barrier(0);
    // 2) stage B(ks+1) -> slot cur^1  (3 vmem)
    {
      const int s2 = (ks + 1 < NSTEP) ? ks + 1 : NSTEP - 1;
      const char* g = wsrc + (size_t)s2 * STEP_BYTES;
      char* d = (cur ^ 1) ? nullptr : nullptr;  // (slot offset applied below)
      char* base = ((cur ^ 1) ? (char*)0 : (char*)0);
      (void)d; (void)base;
      const size_t so = (size_t)(cur ^ 1) * SLOT_LDS;
      gload16(g, ldst0 + so);
      gload16(g + 1024, ldst1 + so);
      gload16(g + 2048, ldst2 + so);
    }
    __builtin_amdgcn_sched_barrier(0);
    // 3) issue A(ks+2) -> ra[cur]  (4 vmem)
    {
      const int sA = (ks + 2 < NSTEP) ? ks + 2 : NSTEP - 1;
      ra[cur][0] = *(const float4*)(xg0 + sA * 32);
      ra[cur][1] = *(const float4*)(xg0 + sA * 32 + 4);
      ra[cur][2] = *(const float4*)(xg1 + sA * 32);
      ra[cur][3] = *(const float4*)(xg1 + sA * 32 + 4);
    }
    __builtin_amdgcn_sched_barrier(0);
    // 4) wait stage(ks): exactly 11 vmem issued after it (4 A + 3 B + 4 A)
    asm volatile("s_waitcnt vmcnt(11)" ::: "memory");
    __builtin_amdgcn_s_barrier();
    __builtin_amdgcn_sched_barrier(0);
    // 5) ds_read B tiles from slot cur + MFMA
    const char* bp = brd + (size_t)cur * SLOT_LDS;
#pragma unroll
    for (int nt = 0; nt < 11; nt++) {
      bf16x8 bf = *(const bf16x8*)(bp + nt * 256);
      acc[0][nt] = __builtin_amdgcn_mfma_f32_16x16x32_bf16(A0.v, bf, acc[0][nt], 0, 0, 0);
      acc[1][nt] = __builtin_amdgcn_mfma_f32_16x16x32_bf16(A1.v, bf, acc[1][nt], 0, 0, 0);
    }
    __builtin_amdgcn_sched_barrier(0);
    // 6) all reads of slot cur done before next iter overwrites it
    __builtin_amdgcn_s_barrier();
  }

  // ---- epilogue: 4 phases of 32 rows. D layout: row=(l>>4)*4+reg, col=l&15.
  for (int p = 0; p < 4; p++) {
    __syncthreads();
    if (wm == p) {
#pragma unroll
      for (int mf = 0; mf < 2; mf++)
#pragma unroll
        for (int nt = 0; nt < 11; nt++)
#pragma unroll
          for (int r = 0; r < 4; r++)
            z[(mf * 16 + ablk * 4 + r) * 357 + wn * 176 + nt * 16 + arow] =
                acc[mf][nt][r];
    }
    __syncthreads();
    if (tid < 64) {
      const int t = tid >> 5, r = tid & 31;
      const float* zr = &z[r * 357];
      float gl[20], m = -1e30f;
#pragma unroll
      for (int u = 0; u < 20; u++) {
        gl[u] = zr[300 + t * 20 + u] + bias[300 + t * 20 + u];
        m = fmaxf(m, gl[u]);
      }
      float pr[20], s = 0.f;
#pragma unroll
      for (int u = 0; u < 20; u++) {
        pr[u] = __expf(gl[u] - m);
        s += pr[u];
      }
      const float inv = 1.f / s;
      const float* Wl = t ? Wv : Wc;
      float wl[10];
#pragma unroll
      for (int h = 0; h < 10; h++) wl[h] = Wl[h];
      float accum = 0.f;
#pragma unroll
      for (int u = 0; u < 10; u++) {
        float d = 0.f;
#pragma unroll
        for (int h = 0; h < 10; h++) {
          int c = t * 100 + u * 10 + h;
          d += fmaxf(zr[c] + bias[c], 0.f) * wl[h];
        }
        accum += pr[u] * d;
      }
#pragma unroll
      for (int u = 0; u < 10; u++) {
        float d = 0.f;
#pragma unroll
        for (int h = 0; h < 10; h++) {
          int c = 200 + u * 10 + h;
          d += fmaxf(zr[c] + bias[c], 0.f) * wl[h];
        }
        accum += pr[10 + u] * d;
      }
      float logit = (t ? bv[0] : bc[0]) + accum * inv;
      out[(size_t)t * BROWS + rowbase + p * 32 + r] =
          1.f / (1.f + __expf(-logit));
    }
  }
}

extern "C" void kernel_launch(void* const* d_in, const int* in_sizes, int n_in,
                              void* d_out, int out_size, void* d_ws, size_t ws_size,
                              hipStream_t stream) {
  const float* x = (const float*)d_in[0];
  const float* Ws = (const float*)d_in[3];
  const float* bs = (const float*)d_in[4];
  const float* Wt = (const float*)d_in[5];
  const float* bt = (const float*)d_in[6];
  const float* Wg = (const float*)d_in[7];
  const float* bg = (const float*)d_in[8];
  const float* Wc = (const float*)d_in[9];
  const float* bc = (const float*)d_in[10];
  const float* Wv = (const float*)d_in[11];
  const float* bv = (const float*)d_in[12];
  unsigned short* Wpack = (unsigned short*)d_ws;
  float* bias = (float*)((char*)d_ws + (size_t)NCOLP * 1024 * 2);
  float* out = (float*)d_out;

  hipLaunchKernelGGL(ple_prep, dim3(NCOLP), dim3(256), 0, stream, Ws, bs, Wt, bt,
                     Wg, bg, Wpack, bias);
  hipLaunchKernelGGL(ple_main, dim3(BROWS / 128), dim3(512), 0, stream, x, Wpack,
                     bias, Wc, bc, Wv, bv, out);
}